// Round 4
// baseline (337.171 us; speedup 1.0000x reference)
//
#include <hip/hip_runtime.h>
#include <hip/hip_bf16.h>

#define N_NODES 50000
#define N_EDGES 800000
#define FEATS 128
#define HEADS 8
#define NF_WAVES 8192

typedef __attribute__((ext_vector_type(8))) short bf16x8;
typedef __attribute__((ext_vector_type(4))) float f32x4;

__device__ __forceinline__ unsigned short f2bf(float f){
  unsigned u = __float_as_uint(f);
  u += 0x7FFF + ((u >> 16) & 1);           // RNE
  return (unsigned short)(u >> 16);
}
__device__ __forceinline__ float bf2f(unsigned h){
  return __uint_as_float(h << 16);
}
__device__ __forceinline__ void unpack8(uint4 p, float* f){
  f[0]=bf2f(p.x & 0xffffu); f[1]=bf2f(p.x >> 16);
  f[2]=bf2f(p.y & 0xffffu); f[3]=bf2f(p.y >> 16);
  f[4]=bf2f(p.z & 0xffffu); f[5]=bf2f(p.z >> 16);
  f[6]=bf2f(p.w & 0xffffu); f[7]=bf2f(p.w >> 16);
}

// ---------------- fused: BN column stats (blocks 0..511) + dst histogram (512..767)
__global__ void stats_hist_kernel(const float* __restrict__ ftq, const float* __restrict__ ftk,
                                  float* __restrict__ sums,
                                  const int* __restrict__ dst, int* __restrict__ counts){
  if (blockIdx.x < 512){
    __shared__ float red[4][FEATS];
    int tid = threadIdx.x;
    for (int i = tid; i < 4*FEATS; i += 256) ((float*)red)[i] = 0.f;
    __syncthreads();
    int c = tid & 127;
    int half = tid >> 7;
    float sq_=0.f, qq_=0.f, sk_=0.f, kk_=0.f;
    for (int r = blockIdx.x*2 + half; r < N_NODES; r += 512*2){
      float xq = ftq[(size_t)r*FEATS + c];
      float xk = ftk[(size_t)r*FEATS + c];
      sq_ += xq; qq_ += xq*xq; sk_ += xk; kk_ += xk*xk;
    }
    atomicAdd(&red[0][c], sq_);
    atomicAdd(&red[1][c], qq_);
    atomicAdd(&red[2][c], sk_);
    atomicAdd(&red[3][c], kk_);
    __syncthreads();
    if (tid < FEATS){
      atomicAdd(&sums[0*FEATS+tid], red[0][tid]);
      atomicAdd(&sums[1*FEATS+tid], red[1][tid]);
      atomicAdd(&sums[2*FEATS+tid], red[2][tid]);
      atomicAdd(&sums[3*FEATS+tid], red[3][tid]);
    }
  } else {
    int b = blockIdx.x - 512;   // 0..255
    for (int t = b*256 + threadIdx.x; t < N_EDGES; t += 256*256)
      atomicAdd(&counts[dst[t]], 1);
  }
}

// ---------------- fused: full 50k exclusive scan (block 0, 1024 thr) + BN-fold (blocks 1..24)
// counts buffer is zero-padded (memset covers 53248 ints), so OOB chunk reads are 0.
__global__ __launch_bounds__(1024) void scan_fold_kernel(
    const int* __restrict__ counts, int* __restrict__ offsets,
    const float* __restrict__ Wq, const float* __restrict__ bq,
    const float* __restrict__ Wk, const float* __restrict__ Wv,
    const float* __restrict__ gq, const float* __restrict__ bqn,
    const float* __restrict__ gk, const float* __restrict__ bkn,
    const float* __restrict__ sums,
    unsigned short* __restrict__ Wb, float* __restrict__ bias){
  if (blockIdx.x == 0){
    __shared__ int bs[1024];
    int t = threadIdx.x;
    int vals[52];
    const uint4* c4 = (const uint4*)counts;
    int base4 = t*13;                       // 13 uint4 = 52 ints, chunk base t*52
    int lsum = 0;
    #pragma unroll
    for (int j = 0; j < 13; j++){
      uint4 w = c4[base4 + j];
      vals[j*4+0] = (int)w.x; vals[j*4+1] = (int)w.y;
      vals[j*4+2] = (int)w.z; vals[j*4+3] = (int)w.w;
      lsum += (int)w.x + (int)w.y + (int)w.z + (int)w.w;
    }
    bs[t] = lsum;
    __syncthreads();
    for (int d = 1; d < 1024; d <<= 1){
      int v = (t >= d) ? bs[t - d] : 0;
      __syncthreads();
      bs[t] += v;
      __syncthreads();
    }
    int run = bs[t] - lsum;                 // exclusive across threads
    int i0 = t*52;
    #pragma unroll
    for (int j = 0; j < 52; j++){
      int i = i0 + j;
      if (i < N_NODES) offsets[i] = run;
      run += vals[j];
    }
    if (t == 1023) offsets[N_NODES] = bs[1023];
  } else {
    int wave = (blockIdx.x - 1)*16 + (threadIdx.x >> 6);   // 0..383
    int lane = threadIdx.x & 63;
    int m = wave >> 7;          // 0=q,1=v,2=k
    int o = wave & 127;
    const float* Wsrc = (m==0) ? Wq : (m==1) ? Wv : Wk;
    const float* g   = (m==2) ? gk : gq;
    const float* bb  = (m==2) ? bkn : bqn;
    const float* s0  = (m==2) ? (sums + 2*FEATS) : sums;
    const float invN = 1.0f / (float)N_NODES;
    float acc = 0.f;
    unsigned short w2[2];
    int i0 = lane*2;
    #pragma unroll
    for (int t = 0; t < 2; t++){
      int i = i0 + t;
      float mean = s0[i]*invN;
      float var  = s0[FEATS+i]*invN - mean*mean;
      float rstd = rsqrtf(var + 1e-5f);
      float scale = g[i]*rstd;
      float shift = bb[i] - mean*scale;
      float w = Wsrc[o*FEATS + i];
      w2[t] = f2bf(w*scale);
      acc += shift*w;
    }
    unsigned pack = (unsigned)w2[0] | ((unsigned)w2[1] << 16);
    ((unsigned*)Wb)[(m*FEATS*FEATS + o*FEATS + i0) >> 1] = pack;
    #pragma unroll
    for (int off = 1; off < 64; off <<= 1) acc += __shfl_xor(acc, off);
    if (lane == 0) bias[m*FEATS + o] = acc + ((m==0) ? bq[o] : 0.f);
  }
}

// ---------------- fused GEMM (y=0: q+v share A-stage; y=1: k) + CSR scatter (y=2)
#define GM 64
__global__ __launch_bounds__(256) void gemm_scatter_kernel(
    const float* __restrict__ ftq, const float* __restrict__ ftk,
    const unsigned short* __restrict__ Wball, const float* __restrict__ biasall,
    unsigned short* __restrict__ qv, unsigned short* __restrict__ kb,
    const int* __restrict__ dst, const int* __restrict__ srcE,
    const int* __restrict__ offsets, int* __restrict__ cursor,
    int* __restrict__ src_csr){
  if (blockIdx.y == 2){
    int t = blockIdx.x*256 + threadIdx.x;
    if (t < N_EDGES){
      int d = dst[t];
      int p = atomicAdd(&cursor[d], 1);
      src_csr[offsets[d] + p] = srcE[t];
    }
    return;
  }
  const int nblk = (N_NODES + GM - 1)/GM;
  if (blockIdx.x >= nblk) return;
  __shared__ unsigned short As[GM][136];
  __shared__ unsigned short Bs[FEATS][136];
  int tid = threadIdx.x;
  int row0 = blockIdx.x * GM;
  const float* X = (blockIdx.y == 1) ? ftk : ftq;
  { // stage A with f32->bf16 convert (once)
    for (int idx = tid; idx < GM*FEATS/4; idx += 256){
      int r = idx >> 5;
      int c4 = (idx & 31) * 4;
      int row = row0 + r;
      float4 xv = make_float4(0.f,0.f,0.f,0.f);
      if (row < N_NODES) xv = *(const float4*)(X + (size_t)row*FEATS + c4);
      unsigned p0 = (unsigned)f2bf(xv.x) | ((unsigned)f2bf(xv.y) << 16);
      unsigned p1 = (unsigned)f2bf(xv.z) | ((unsigned)f2bf(xv.w) << 16);
      *(unsigned*)&As[r][c4]   = p0;
      *(unsigned*)&As[r][c4+2] = p1;
    }
  }
  int wave = tid >> 6, lane = tid & 63;
  int r0 = wave * 16;
  int mrow = lane & 15, quad = lane >> 4;
  int mfirst = (blockIdx.y == 1) ? 2 : 0;
  int mlast  = (blockIdx.y == 1) ? 2 : 1;
  for (int m = mfirst; m <= mlast; m++){
    { // stage B (bf16, dwordx4)
      const uint4* srcp = (const uint4*)(Wball + m*FEATS*FEATS);
      for (int idx = tid; idx < FEATS*FEATS/8; idx += 256){
        int n = idx >> 4;
        int kk = (idx & 15) * 8;
        *(uint4*)&Bs[n][kk] = srcp[idx];
      }
    }
    __syncthreads();
    f32x4 acc[8];
    #pragma unroll
    for (int i = 0; i < 8; i++) acc[i] = (f32x4){0.f,0.f,0.f,0.f};
    #pragma unroll
    for (int kt = 0; kt < 4; kt++){
      int kbk = kt*32 + quad*8;
      bf16x8 a = *(bf16x8*)&As[r0 + mrow][kbk];
      #pragma unroll
      for (int ct = 0; ct < 8; ct++){
        bf16x8 b = *(bf16x8*)&Bs[ct*16 + mrow][kbk];
        acc[ct] = __builtin_amdgcn_mfma_f32_16x16x32_bf16(a, b, acc[ct], 0, 0, 0);
      }
    }
    unsigned short* Out = (m==2) ? kb : (qv + m*128);
    const int ostride = (m==2) ? FEATS : 256;
    const float* bias = biasall + m*FEATS;
    #pragma unroll
    for (int ct = 0; ct < 8; ct++){
      int col = ct*16 + mrow;
      float bv = bias[col];
      #pragma unroll
      for (int v = 0; v < 4; v++){
        int row = row0 + r0 + quad*4 + v;
        if (row < N_NODES)
          Out[(size_t)row*ostride + col] = f2bf(acc[ct][v] + bv);
      }
    }
    __syncthreads();   // Bs reads complete before restage
  }
}

// ---------------- fused per-dst-node: scores + unnormalized agg + divide (persistent waves)
__global__ __launch_bounds__(256) void node_fused_kernel(
    const unsigned short* __restrict__ qv, const unsigned short* __restrict__ kb,
    const float* __restrict__ attn, const int* __restrict__ src_csr,
    const int* __restrict__ offsets, float* __restrict__ out){
  int lane = threadIdx.x & 63;
  int h = lane & 7, g = lane >> 3;
  int w = blockIdx.x*4 + (threadIdx.x >> 6);
  const float L2E = 1.44269504f;
  float ar[16];
  {
    const uint4* ap = (const uint4*)(attn + h*16);
    uint4 a0 = ap[0], a1 = ap[1], a2 = ap[2], a3 = ap[3];
    ar[0]=__uint_as_float(a0.x); ar[1]=__uint_as_float(a0.y); ar[2]=__uint_as_float(a0.z); ar[3]=__uint_as_float(a0.w);
    ar[4]=__uint_as_float(a1.x); ar[5]=__uint_as_float(a1.y); ar[6]=__uint_as_float(a1.z); ar[7]=__uint_as_float(a1.w);
    ar[8]=__uint_as_float(a2.x); ar[9]=__uint_as_float(a2.y); ar[10]=__uint_as_float(a2.z); ar[11]=__uint_as_float(a2.w);
    ar[12]=__uint_as_float(a3.x); ar[13]=__uint_as_float(a3.y); ar[14]=__uint_as_float(a3.z); ar[15]=__uint_as_float(a3.w);
  }
  for (int n = w; n < N_NODES; n += NF_WAVES){
    int off0 = offsets[n];
    int deg = offsets[n+1] - off0;
    if (deg == 0){
      ((float2*)(out + (size_t)n*FEATS))[lane] = make_float2(0.f, 0.f);
      continue;
    }
    float kf2[16];
    {
      const unsigned short* kr = kb + (size_t)n*FEATS + h*16;
      uint4 k0 = *(const uint4*)kr;
      uint4 k1 = *(const uint4*)(kr + 8);
      float kf[16]; unpack8(k0, kf); unpack8(k1, kf+8);
      #pragma unroll
      for (int i = 0; i < 16; i++) kf2[i] = -L2E * kf[i];
    }
    float ssum = 0.f;
    float acc[16];
    #pragma unroll
    for (int i = 0; i < 16; i++) acc[i] = 0.f;
    int s_next = (g < deg) ? src_csr[off0 + g] : 0;
    for (int j = g; j < deg; j += 8){
      int s = s_next;
      if (j + 8 < deg) s_next = src_csr[off0 + j + 8];
      const unsigned short* qr = qv + (size_t)s*256 + h*16;
      uint4 q0 = *(const uint4*)qr;
      uint4 q1 = *(const uint4*)(qr + 8);
      uint4 v0 = *(const uint4*)(qr + 128);     // v half of the interleaved row
      uint4 v1 = *(const uint4*)(qr + 136);
      float qf[16]; unpack8(q0, qf); unpack8(q1, qf+8);
      float t = 0.f;
      #pragma unroll
      for (int i = 0; i < 16; i++){
        // sigmoid(q+k) = 1/(1+2^(-(q+k)*log2e)); fold -log2e*k into kf2
        float xs = fmaf(qf[i], -L2E, kf2[i]);
        float sg = __builtin_amdgcn_rcpf(1.f + __builtin_amdgcn_exp2f(xs));
        t = fmaf(ar[i], sg, t);
      }
      float ex = __builtin_amdgcn_exp2f(t * L2E);  // |t|<=sum|attn| -> no overflow, max-free
      ssum += ex;
      float vf[16]; unpack8(v0, vf); unpack8(v1, vf+8);
      #pragma unroll
      for (int i = 0; i < 16; i++) acc[i] = fmaf(ex, vf[i], acc[i]);
    }
    ssum += __shfl_xor(ssum, 8); ssum += __shfl_xor(ssum, 16); ssum += __shfl_xor(ssum, 32);
    #pragma unroll
    for (int i = 0; i < 16; i++){
      acc[i] += __shfl_xor(acc[i], 8);
      acc[i] += __shfl_xor(acc[i], 16);
      acc[i] += __shfl_xor(acc[i], 32);
    }
    if (g == 0){
      float inv_s = 1.f / ssum;
      float4* op = (float4*)(out + (size_t)n*FEATS + h*16);
      op[0] = make_float4(acc[0]*inv_s, acc[1]*inv_s, acc[2]*inv_s, acc[3]*inv_s);
      op[1] = make_float4(acc[4]*inv_s, acc[5]*inv_s, acc[6]*inv_s, acc[7]*inv_s);
      op[2] = make_float4(acc[8]*inv_s, acc[9]*inv_s, acc[10]*inv_s, acc[11]*inv_s);
      op[3] = make_float4(acc[12]*inv_s, acc[13]*inv_s, acc[14]*inv_s, acc[15]*inv_s);
    }
  }
}

extern "C" void kernel_launch(void* const* d_in, const int* in_sizes, int n_in,
                              void* d_out, int out_size, void* d_ws, size_t ws_size,
                              hipStream_t stream){
  (void)in_sizes; (void)n_in; (void)out_size; (void)ws_size;
  const float* ftq  = (const float*)d_in[0];
  const float* ftk  = (const float*)d_in[1];
  const int*   src  = (const int*)d_in[2];
  const int*   dst  = (const int*)d_in[3];
  const float* Wq   = (const float*)d_in[4];
  const float* bq   = (const float*)d_in[5];
  const float* Wk   = (const float*)d_in[6];
  const float* Wv   = (const float*)d_in[7];
  const float* attn = (const float*)d_in[8];
  const float* gq   = (const float*)d_in[9];
  const float* bqn  = (const float*)d_in[10];
  const float* gk   = (const float*)d_in[11];
  const float* bkn  = (const float*)d_in[12];

  char* ws = (char*)d_ws;
  int*   counts  = (int*)(ws + 0);            // 200000 B (+ zero pad into cursor for scan OOB)
  int*   cursor  = (int*)(ws + 200000);       // 200000 B
  float* sums    = (float*)(ws + 400000);     // 2048 B (zero region ends 402048)
  int*   offsets = (int*)(ws + 402048);       // 200004 B
  int*   src_csr = (int*)(ws + 604112);       // 3.2e6 B
  unsigned short* Wb   = (unsigned short*)(ws + 3804112);  // 98304 B
  float* biasf   = (float*)(ws + 3902416);    // 1536 B
  unsigned short* qv = (unsigned short*)(ws + 3903952);    // 50000*256*2 = 25.6e6 B
  unsigned short* kb = qv + (size_t)N_NODES*256;           // 12.8e6 B
  float* out = (float*)d_out;

  hipMemsetAsync(ws, 0, 402048, stream);  // counts, cursor, bn sums

  hipLaunchKernelGGL(stats_hist_kernel, dim3(768), dim3(256), 0, stream,
                     ftq, ftk, sums, dst, counts);
  hipLaunchKernelGGL(scan_fold_kernel, dim3(25), dim3(1024), 0, stream,
                     counts, offsets,
                     Wq, bq, Wk, Wv, gq, bqn, gk, bkn, sums, Wb, biasf);
  hipLaunchKernelGGL(gemm_scatter_kernel, dim3((N_EDGES+255)/256, 3), dim3(256), 0, stream,
                     ftq, ftk, Wb, biasf, qv, kb, dst, src, offsets, cursor, src_csr);
  hipLaunchKernelGGL(node_fused_kernel, dim3(NF_WAVES/4), dim3(256), 0, stream,
                     qv, kb, attn, src_csr, offsets, out);
}

// Round 5
// 332.851 us; speedup vs baseline: 1.0130x; 1.0130x over previous
//
#include <hip/hip_runtime.h>
#include <hip/hip_bf16.h>

#define N_NODES 50000
#define N_EDGES 800000
#define FEATS 128
#define HEADS 8
#define NF_WAVES 8192

typedef __attribute__((ext_vector_type(8))) short bf16x8;
typedef __attribute__((ext_vector_type(4))) float f32x4;

__device__ __forceinline__ unsigned short f2bf(float f){
  unsigned u = __float_as_uint(f);
  u += 0x7FFF + ((u >> 16) & 1);           // RNE
  return (unsigned short)(u >> 16);
}
// bf16 pair unpack, 1 VALU op per float (lo: shl; hi: and-mask)
__device__ __forceinline__ void unpack8(uint4 p, float* f){
  f[0]=__uint_as_float(p.x << 16); f[1]=__uint_as_float(p.x & 0xffff0000u);
  f[2]=__uint_as_float(p.y << 16); f[3]=__uint_as_float(p.y & 0xffff0000u);
  f[4]=__uint_as_float(p.z << 16); f[5]=__uint_as_float(p.z & 0xffff0000u);
  f[6]=__uint_as_float(p.w << 16); f[7]=__uint_as_float(p.w & 0xffff0000u);
}

// ---------------- fused: BN column stats (blocks 0..511) + dst histogram (512..767)
__global__ void stats_hist_kernel(const float* __restrict__ ftq, const float* __restrict__ ftk,
                                  float* __restrict__ sums,
                                  const int* __restrict__ dst, int* __restrict__ counts){
  if (blockIdx.x < 512){
    __shared__ float red[4][FEATS];
    int tid = threadIdx.x;
    for (int i = tid; i < 4*FEATS; i += 256) ((float*)red)[i] = 0.f;
    __syncthreads();
    int c = tid & 127;
    int half = tid >> 7;
    float sq_=0.f, qq_=0.f, sk_=0.f, kk_=0.f;
    for (int r = blockIdx.x*2 + half; r < N_NODES; r += 512*2){
      float xq = ftq[(size_t)r*FEATS + c];
      float xk = ftk[(size_t)r*FEATS + c];
      sq_ += xq; qq_ += xq*xq; sk_ += xk; kk_ += xk*xk;
    }
    atomicAdd(&red[0][c], sq_);
    atomicAdd(&red[1][c], qq_);
    atomicAdd(&red[2][c], sk_);
    atomicAdd(&red[3][c], kk_);
    __syncthreads();
    if (tid < FEATS){
      atomicAdd(&sums[0*FEATS+tid], red[0][tid]);
      atomicAdd(&sums[1*FEATS+tid], red[1][tid]);
      atomicAdd(&sums[2*FEATS+tid], red[2][tid]);
      atomicAdd(&sums[3*FEATS+tid], red[3][tid]);
    }
  } else {
    int b = blockIdx.x - 512;   // 0..255
    for (int t = b*256 + threadIdx.x; t < N_EDGES; t += 256*256)
      atomicAdd(&counts[dst[t]], 1);
  }
}

// ---------------- fused: full 50k exclusive scan (block 0, 1024 thr) + BN-fold (blocks 1..24)
// counts buffer is zero-padded (memset covers region), so OOB chunk reads are 0.
__global__ __launch_bounds__(1024) void scan_fold_kernel(
    const int* __restrict__ counts, int* __restrict__ offsets,
    const float* __restrict__ Wq, const float* __restrict__ bq,
    const float* __restrict__ Wk, const float* __restrict__ Wv,
    const float* __restrict__ gq, const float* __restrict__ bqn,
    const float* __restrict__ gk, const float* __restrict__ bkn,
    const float* __restrict__ sums,
    unsigned short* __restrict__ Wb, float* __restrict__ bias){
  if (blockIdx.x == 0){
    __shared__ int bs[1024];
    int t = threadIdx.x;
    int vals[52];
    const uint4* c4 = (const uint4*)counts;
    int base4 = t*13;                       // 13 uint4 = 52 ints, chunk base t*52
    int lsum = 0;
    #pragma unroll
    for (int j = 0; j < 13; j++){
      uint4 w = c4[base4 + j];
      vals[j*4+0] = (int)w.x; vals[j*4+1] = (int)w.y;
      vals[j*4+2] = (int)w.z; vals[j*4+3] = (int)w.w;
      lsum += (int)w.x + (int)w.y + (int)w.z + (int)w.w;
    }
    bs[t] = lsum;
    __syncthreads();
    for (int d = 1; d < 1024; d <<= 1){
      int v = (t >= d) ? bs[t - d] : 0;
      __syncthreads();
      bs[t] += v;
      __syncthreads();
    }
    int run = bs[t] - lsum;                 // exclusive across threads
    int i0 = t*52;
    #pragma unroll
    for (int j = 0; j < 52; j++){
      int i = i0 + j;
      if (i < N_NODES) offsets[i] = run;
      run += vals[j];
    }
    if (t == 1023) offsets[N_NODES] = bs[1023];
  } else {
    int wave = (blockIdx.x - 1)*16 + (threadIdx.x >> 6);   // 0..383
    int lane = threadIdx.x & 63;
    int m = wave >> 7;          // 0=q,1=v,2=k
    int o = wave & 127;
    const float* Wsrc = (m==0) ? Wq : (m==1) ? Wv : Wk;
    const float* g   = (m==2) ? gk : gq;
    const float* bb  = (m==2) ? bkn : bqn;
    const float* s0  = (m==2) ? (sums + 2*FEATS) : sums;
    const float invN = 1.0f / (float)N_NODES;
    float acc = 0.f;
    unsigned short w2[2];
    int i0 = lane*2;
    #pragma unroll
    for (int t = 0; t < 2; t++){
      int i = i0 + t;
      float mean = s0[i]*invN;
      float var  = s0[FEATS+i]*invN - mean*mean;
      float rstd = rsqrtf(var + 1e-5f);
      float scale = g[i]*rstd;
      float shift = bb[i] - mean*scale;
      float w = Wsrc[o*FEATS + i];
      w2[t] = f2bf(w*scale);
      acc += shift*w;
    }
    unsigned pack = (unsigned)w2[0] | ((unsigned)w2[1] << 16);
    ((unsigned*)Wb)[(m*FEATS*FEATS + o*FEATS + i0) >> 1] = pack;
    #pragma unroll
    for (int off = 1; off < 64; off <<= 1) acc += __shfl_xor(acc, off);
    if (lane == 0) bias[m*FEATS + o] = acc + ((m==0) ? bq[o] : 0.f);
  }
}

// ---------------- CSR scatter (standalone: zero LDS -> full occupancy)
__global__ void scatter_kernel(const int* __restrict__ dst, const int* __restrict__ srcE,
                               const int* __restrict__ offsets,
                               int* __restrict__ cursor, int* __restrict__ src_csr){
  int t = blockIdx.x*256 + threadIdx.x;
  if (t < N_EDGES){
    int d = dst[t];
    int p = atomicAdd(&cursor[d], 1);
    src_csr[offsets[d] + p] = srcE[t];
  }
}

// ---------------- bf16 MFMA GEMM: A fragments global->registers, B-only LDS.
// plane 0: q+v from ftq (two B-passes share reg-A); plane 1: k from ftk.
#define GM 64
__global__ __launch_bounds__(256) void gemm_kernel(
    const float* __restrict__ ftq, const float* __restrict__ ftk,
    const unsigned short* __restrict__ Wball, const float* __restrict__ biasall,
    unsigned short* __restrict__ qv, unsigned short* __restrict__ kb){
  __shared__ unsigned short Bs[FEATS][136];   // 34.8 KB -> 4 blocks/CU
  int tid = threadIdx.x;
  int wave = tid >> 6, lane = tid & 63;
  int mrow = lane & 15, quad = lane >> 4;
  int row0 = blockIdx.x * GM;
  int plane = blockIdx.y;
  const float* X = plane ? ftk : ftq;
  int arow = row0 + wave*16 + mrow;
  bool rok = arow < N_NODES;
  size_t abase = (size_t)(rok ? arow : 0) * FEATS;
  // A fragments: 4 kt x 8 bf16 per lane (f32 loaded as 2x float4, converted in-reg)
  bf16x8 afrag[4];
  #pragma unroll
  for (int kt = 0; kt < 4; kt++){
    const float* xp = X + abase + kt*32 + quad*8;
    float4 x0 = *(const float4*)xp;
    float4 x1 = *(const float4*)(xp + 4);
    if (!rok){ x0 = make_float4(0.f,0.f,0.f,0.f); x1 = x0; }
    bf16x8 a;
    a[0]=(short)f2bf(x0.x); a[1]=(short)f2bf(x0.y); a[2]=(short)f2bf(x0.z); a[3]=(short)f2bf(x0.w);
    a[4]=(short)f2bf(x1.x); a[5]=(short)f2bf(x1.y); a[6]=(short)f2bf(x1.z); a[7]=(short)f2bf(x1.w);
    afrag[kt] = a;
  }
  int mfirst = plane ? 2 : 0;
  int mlast  = plane ? 2 : 1;
  for (int m = mfirst; m <= mlast; m++){
    { // stage B (bf16, dwordx4; conflict-free: stride 17 chunks)
      const uint4* srcp = (const uint4*)(Wball + m*FEATS*FEATS);
      for (int idx = tid; idx < FEATS*FEATS/8; idx += 256){
        int n = idx >> 4;
        int kk = (idx & 15) * 8;
        *(uint4*)&Bs[n][kk] = srcp[idx];
      }
    }
    __syncthreads();
    f32x4 acc[8];
    #pragma unroll
    for (int i = 0; i < 8; i++) acc[i] = (f32x4){0.f,0.f,0.f,0.f};
    #pragma unroll
    for (int kt = 0; kt < 4; kt++){
      int kbk = kt*32 + quad*8;
      #pragma unroll
      for (int ct = 0; ct < 8; ct++){
        bf16x8 b = *(bf16x8*)&Bs[ct*16 + mrow][kbk];
        acc[ct] = __builtin_amdgcn_mfma_f32_16x16x32_bf16(afrag[kt], b, acc[ct], 0, 0, 0);
      }
    }
    unsigned short* Out = (m==2) ? kb : (qv + m*128);
    const int ostride = (m==2) ? FEATS : 256;
    const float* bias = biasall + m*FEATS;
    #pragma unroll
    for (int ct = 0; ct < 8; ct++){
      int col = ct*16 + mrow;
      float bv = bias[col];
      #pragma unroll
      for (int v = 0; v < 4; v++){
        int orow = row0 + wave*16 + quad*4 + v;
        unsigned ub = f2bf(acc[ct][v] + bv);
        unsigned partner = (unsigned)__shfl_xor((int)ub, 1);
        if (!(mrow & 1) && orow < N_NODES){
          unsigned pk = ub | (partner << 16);
          *(unsigned*)&Out[(size_t)orow*ostride + col] = pk;
        }
      }
    }
    __syncthreads();   // Bs reads complete before restage
  }
}

// ---------------- fused per-dst-node: scores + unnormalized agg + divide (persistent waves)
__global__ __launch_bounds__(256) void node_fused_kernel(
    const unsigned short* __restrict__ qv, const unsigned short* __restrict__ kb,
    const float* __restrict__ attn, const int* __restrict__ src_csr,
    const int* __restrict__ offsets, float* __restrict__ out){
  int lane = threadIdx.x & 63;
  int h = lane & 7, g = lane >> 3;
  int w = blockIdx.x*4 + (threadIdx.x >> 6);
  const float L2E = 1.44269504f;
  float ar[16], arp[8];
  {
    const uint4* ap = (const uint4*)(attn + h*16);
    uint4 a0 = ap[0], a1 = ap[1], a2 = ap[2], a3 = ap[3];
    ar[0]=__uint_as_float(a0.x); ar[1]=__uint_as_float(a0.y); ar[2]=__uint_as_float(a0.z); ar[3]=__uint_as_float(a0.w);
    ar[4]=__uint_as_float(a1.x); ar[5]=__uint_as_float(a1.y); ar[6]=__uint_as_float(a1.z); ar[7]=__uint_as_float(a1.w);
    ar[8]=__uint_as_float(a2.x); ar[9]=__uint_as_float(a2.y); ar[10]=__uint_as_float(a2.z); ar[11]=__uint_as_float(a2.w);
    ar[12]=__uint_as_float(a3.x); ar[13]=__uint_as_float(a3.y); ar[14]=__uint_as_float(a3.z); ar[15]=__uint_as_float(a3.w);
    #pragma unroll
    for (int p = 0; p < 8; p++) arp[p] = ar[2*p] + ar[2*p+1];
  }
  for (int n = w; n < N_NODES; n += NF_WAVES){
    int off0 = offsets[n];
    int deg = offsets[n+1] - off0;
    if (deg == 0){
      ((float2*)(out + (size_t)n*FEATS))[lane] = make_float2(0.f, 0.f);
      continue;
    }
    float kf2[16];
    {
      const unsigned short* kr = kb + (size_t)n*FEATS + h*16;
      uint4 k0 = *(const uint4*)kr;
      uint4 k1 = *(const uint4*)(kr + 8);
      float kf[16]; unpack8(k0, kf); unpack8(k1, kf+8);
      #pragma unroll
      for (int i = 0; i < 16; i++) kf2[i] = -L2E * kf[i];
    }
    float ssum = 0.f;
    float acc[16];
    #pragma unroll
    for (int i = 0; i < 16; i++) acc[i] = 0.f;
    int s_next = (g < deg) ? src_csr[off0 + g] : 0;
    for (int j = g; j < deg; j += 8){
      int s = s_next;
      if (j + 8 < deg) s_next = src_csr[off0 + j + 8];
      const unsigned short* qr = qv + (size_t)s*256 + h*16;
      uint4 q0 = *(const uint4*)qr;
      uint4 q1 = *(const uint4*)(qr + 8);
      uint4 v0 = *(const uint4*)(qr + 128);     // v half of the interleaved row
      uint4 v1 = *(const uint4*)(qr + 136);
      float qf[16]; unpack8(q0, qf); unpack8(q1, qf+8);
      // paired sigmoid: a0*sig(x0)+a1*sig(x1) = (a0+a1 + a0*z1 + a1*z0) / ((1+z0)(1+z1)),
      // z_i = 2^(-L2E*x_i); halves the rcp count vs per-feat form.
      float t = 0.f;
      #pragma unroll
      for (int p = 0; p < 8; p++){
        float xs0 = fmaf(qf[2*p],   -L2E, kf2[2*p]);
        float xs1 = fmaf(qf[2*p+1], -L2E, kf2[2*p+1]);
        float z0 = __builtin_amdgcn_exp2f(xs0);
        float z1 = __builtin_amdgcn_exp2f(xs1);
        float d  = (1.f + z0) * (1.f + z1);
        float nu = fmaf(ar[2*p], z1, fmaf(ar[2*p+1], z0, arp[p]));
        t = fmaf(nu, __builtin_amdgcn_rcpf(d), t);
      }
      float ex = __builtin_amdgcn_exp2f(t * L2E);  // |t|<=sum|attn| -> no overflow, max-free
      ssum += ex;
      float vf[16]; unpack8(v0, vf); unpack8(v1, vf+8);
      #pragma unroll
      for (int i = 0; i < 16; i++) acc[i] = fmaf(ex, vf[i], acc[i]);
    }
    ssum += __shfl_xor(ssum, 8); ssum += __shfl_xor(ssum, 16); ssum += __shfl_xor(ssum, 32);
    #pragma unroll
    for (int i = 0; i < 16; i++){
      acc[i] += __shfl_xor(acc[i], 8);
      acc[i] += __shfl_xor(acc[i], 16);
      acc[i] += __shfl_xor(acc[i], 32);
    }
    if (g == 0){
      float inv_s = 1.f / ssum;
      float4* op = (float4*)(out + (size_t)n*FEATS + h*16);
      op[0] = make_float4(acc[0]*inv_s, acc[1]*inv_s, acc[2]*inv_s, acc[3]*inv_s);
      op[1] = make_float4(acc[4]*inv_s, acc[5]*inv_s, acc[6]*inv_s, acc[7]*inv_s);
      op[2] = make_float4(acc[8]*inv_s, acc[9]*inv_s, acc[10]*inv_s, acc[11]*inv_s);
      op[3] = make_float4(acc[12]*inv_s, acc[13]*inv_s, acc[14]*inv_s, acc[15]*inv_s);
    }
  }
}

extern "C" void kernel_launch(void* const* d_in, const int* in_sizes, int n_in,
                              void* d_out, int out_size, void* d_ws, size_t ws_size,
                              hipStream_t stream){
  (void)in_sizes; (void)n_in; (void)out_size; (void)ws_size;
  const float* ftq  = (const float*)d_in[0];
  const float* ftk  = (const float*)d_in[1];
  const int*   src  = (const int*)d_in[2];
  const int*   dst  = (const int*)d_in[3];
  const float* Wq   = (const float*)d_in[4];
  const float* bq   = (const float*)d_in[5];
  const float* Wk   = (const float*)d_in[6];
  const float* Wv   = (const float*)d_in[7];
  const float* attn = (const float*)d_in[8];
  const float* gq   = (const float*)d_in[9];
  const float* bqn  = (const float*)d_in[10];
  const float* gk   = (const float*)d_in[11];
  const float* bkn  = (const float*)d_in[12];

  char* ws = (char*)d_ws;
  int*   counts  = (int*)(ws + 0);            // 200000 B (zero pad into cursor covers scan OOB)
  int*   cursor  = (int*)(ws + 200000);       // 200000 B
  float* sums    = (float*)(ws + 400000);     // 2048 B (zero region ends 402048)
  int*   offsets = (int*)(ws + 402048);       // 200004 B
  int*   src_csr = (int*)(ws + 604112);       // 3.2e6 B
  unsigned short* Wb   = (unsigned short*)(ws + 3804112);  // 98304 B
  float* biasf   = (float*)(ws + 3902416);    // 1536 B
  unsigned short* qv = (unsigned short*)(ws + 3903952);    // 50000*256*2 = 25.6e6 B
  unsigned short* kb = qv + (size_t)N_NODES*256;           // 12.8e6 B
  float* out = (float*)d_out;

  hipMemsetAsync(ws, 0, 402048, stream);  // counts, cursor, bn sums

  hipLaunchKernelGGL(stats_hist_kernel, dim3(768), dim3(256), 0, stream,
                     ftq, ftk, sums, dst, counts);
  hipLaunchKernelGGL(scan_fold_kernel, dim3(25), dim3(1024), 0, stream,
                     counts, offsets,
                     Wq, bq, Wk, Wv, gq, bqn, gk, bkn, sums, Wb, biasf);
  hipLaunchKernelGGL(scatter_kernel, dim3((N_EDGES+255)/256), dim3(256), 0, stream,
                     dst, src, offsets, cursor, src_csr);
  hipLaunchKernelGGL(gemm_kernel, dim3((N_NODES+GM-1)/GM, 2), dim3(256), 0, stream,
                     ftq, ftk, Wb, biasf, qv, kb);
  hipLaunchKernelGGL(node_fused_kernel, dim3(NF_WAVES/4), dim3(256), 0, stream,
                     qv, kb, attn, src_csr, offsets, out);
}